// Round 3
// baseline (7341.695 us; speedup 1.0000x reference)
//
#include <hip/hip_runtime.h>
#include <hip/hip_bf16.h>

typedef __hip_bfloat16 bf16;

#define BNS 0.9999950000374997f  /* 1/sqrt(1+1e-5) */

__device__ __forceinline__ float bf2f(bf16 v) { return __bfloat162float(v); }
__device__ __forceinline__ float geluf(float x) { return 0.5f * x * (1.0f + erff(x * 0.70710678118654752f)); }
__device__ __forceinline__ float sigmf(float x) { return 1.0f / (1.0f + expf(-x)); }

// ---------------- PA branch: fused 1x1(64->256)+bn+gelu+1x1(256->64)+sigmoid gate ----------
__global__ __launch_bounds__(256) void k_pa(const float* __restrict__ x,
    const float* __restrict__ w1, const float* __restrict__ g1, const float* __restrict__ b1,
    const float* __restrict__ w2, float* __restrict__ x1pa, bf16* __restrict__ xa) {
  __shared__ float xs[16][65];
  __shared__ float hs[16][257];
  int t = threadIdx.x;
  int b = blockIdx.x / 576;
  int hw0 = (blockIdx.x % 576) * 16;
  for (int i = t; i < 16 * 64; i += 256) {
    int p = i >> 6, c = i & 63;
    xs[p][c] = x[(b * 256 + c) * 9216 + hw0 + p];
  }
  __syncthreads();
  {
    int k = t;
    float gg = g1[k] * BNS, bb = b1[k];
    const float* wr = w1 + k * 64;
    for (int p = 0; p < 16; ++p) {
      float acc = 0.f;
      for (int j = 0; j < 64; ++j) acc += wr[j] * xs[p][j];
      hs[p][k] = geluf(acc * gg + bb);
    }
  }
  __syncthreads();
  for (int i = t; i < 16 * 64; i += 256) {
    int p = i & 15, c = i >> 4;
    float acc = 0.f;
    const float* wr = w2 + c * 256;
    for (int k = 0; k < 256; ++k) acc += wr[k] * hs[p][k];
    float x1v = xs[p][c];
    float pa = x1v * sigmf(acc);
    x1pa[(b * 64 + c) * 9216 + hw0 + p] = pa;
    xa[(b * 256 + c) * 9216 + hw0 + p] = __float2bfloat16(x1v + pa);
  }
}

// ---------------- generic 1x1 conv: inA (fp32, CinA ch) [+ x slice (fp32, CinB ch)] --------
__global__ __launch_bounds__(256) void k_conv1x1(const float* __restrict__ inA, int CinA,
    const float* __restrict__ xsrc, int xoff, int CinB,
    const float* __restrict__ w, const float* __restrict__ bias, int act,
    float* __restrict__ out, int Cout, int npix) {
  __shared__ float s[128][64];
  int t = threadIdx.x;
  int p0 = blockIdx.x * 64;
  int b = p0 / npix;
  int hw0 = p0 % npix;
  int Cin = CinA + CinB;
  for (int i = t; i < Cin * 64; i += 256) {
    int cch = i >> 6, p = i & 63;
    float v;
    if (cch < CinA) v = inA[(b * CinA + cch) * npix + hw0 + p];
    else v = xsrc[(b * 256 + xoff + (cch - CinA)) * 9216 + hw0 + p];
    s[cch][p] = v;
  }
  __syncthreads();
  int px = t & 63;
  for (int c = (t >> 6); c < Cout; c += 4) {
    float acc = bias ? bias[c] : 0.0f;
    const float* wr = w + c * Cin;
    for (int j = 0; j < Cin; ++j) acc += wr[j] * s[j][px];
    if (act == 1) acc = geluf(acc);
    out[(b * Cout + c) * npix + hw0 + px] = acc;
  }
}

// ---------------- la: 3x3 conv 64->64 pad1 + bn + gelu, writes xa channels 64..127 ---------
__global__ __launch_bounds__(256) void k_la(const float* __restrict__ in,
    const float* __restrict__ w, const float* __restrict__ g, const float* __restrict__ bb,
    bf16* __restrict__ xa) {
  int bid = blockIdx.x;
  int tile = bid % 36; int co = (bid / 36) % 64; int b = bid / (36 * 64);
  int th0 = (tile / 6) * 16, tw0 = (tile % 6) * 16;
  int t = threadIdx.x; int ty = t >> 4, tx = t & 15;
  __shared__ float s[18][18];
  float acc = 0.f;
  for (int ci = 0; ci < 64; ++ci) {
    __syncthreads();
    for (int i = t; i < 18 * 18; i += 256) {
      int iy = i / 18, ix = i % 18;
      int y = th0 - 1 + iy, xx = tw0 - 1 + ix;
      float v = 0.f;
      if (y >= 0 && y < 96 && xx >= 0 && xx < 96) v = in[(b * 64 + ci) * 9216 + y * 96 + xx];
      s[iy][ix] = v;
    }
    __syncthreads();
    const float* wr = w + (co * 64 + ci) * 9;
    for (int ky = 0; ky < 3; ++ky)
      for (int kx = 0; kx < 3; ++kx)
        acc += wr[ky * 3 + kx] * s[ty + ky][tx + kx];
  }
  float r = geluf(acc * (g[co] * BNS) + bb[co]);
  xa[(b * 256 + 64 + co) * 9216 + (th0 + ty) * 96 + (tw0 + tx)] = __float2bfloat16(r);
}

// ---------------- maxpool3 (3x3, stride1, pad1, -inf) on x3 -> fp32 -------------------------
__global__ __launch_bounds__(256) void k_maxpool3(const float* __restrict__ x, float* __restrict__ out) {
  int idx = blockIdx.x * 256 + threadIdx.x;
  if (idx >= 16 * 64 * 9216) return;
  int wpx = idx % 96; int tmp = idx / 96; int h = tmp % 96; tmp /= 96; int c = tmp % 64; int b = tmp / 64;
  const float* src = x + (b * 256 + 128 + c) * 9216;
  float m = -3.4e38f;
  for (int dy = -1; dy <= 1; ++dy) {
    int y = h + dy; if ((unsigned)y >= 96u) continue;
    for (int dx = -1; dx <= 1; ++dx) {
      int xx = wpx + dx; if ((unsigned)xx >= 96u) continue;
      m = fmaxf(m, src[y * 96 + xx]);
    }
  }
  out[idx] = m;
}

// ---------------- blurpool: reflect pad (1,2), 4x4 blur, stride 3: 96->32 ------------------
__global__ __launch_bounds__(256) void k_blur(const float* __restrict__ in, float* __restrict__ out) {
  int idx = blockIdx.x * 256 + threadIdx.x;
  if (idx >= 16 * 64 * 1024) return;
  int ow = idx % 32; int tmp = idx / 32; int oh = tmp % 32; int bc = tmp / 32;
  const float* src = in + bc * 9216;
  const float a4[4] = {1.f, 3.f, 3.f, 1.f};
  float s = 0.f;
  for (int ky = 0; ky < 4; ++ky) {
    int sy = 3 * oh + ky - 1; if (sy < 0) sy = -sy; if (sy > 95) sy = 190 - sy;
    for (int kx = 0; kx < 4; ++kx) {
      int sx = 3 * ow + kx - 1; if (sx < 0) sx = -sx; if (sx > 95) sx = 190 - sx;
      s += a4[ky] * a4[kx] * src[sy * 96 + sx];
    }
  }
  out[idx] = s * (1.0f / 64.0f);
}

// ---------------- generic depthwise conv (B=16, C=64) --------------------------------------
__global__ __launch_bounds__(256) void k_dw(const float* __restrict__ in, const float* __restrict__ w,
    const float* __restrict__ bias, float* __restrict__ out,
    int H, int W, int KH, int KW, int pH, int pW, int dil, int accf) {
  int idx = blockIdx.x * 256 + threadIdx.x;
  int total = 16 * 64 * H * W; if (idx >= total) return;
  int wpx = idx % W; int tmp = idx / W; int h = tmp % H; tmp /= H; int c = tmp % 64;
  const float* src = in + tmp * H * W;
  const float* wr = w + c * KH * KW;
  float a = bias ? bias[c] : 0.f;
  for (int ky = 0; ky < KH; ++ky) {
    int y = h - pH + ky * dil; if ((unsigned)y >= (unsigned)H) continue;
    for (int kx = 0; kx < KW; ++kx) {
      int xx = wpx - pW + kx * dil; if ((unsigned)xx >= (unsigned)W) continue;
      a += wr[ky * KW + kx] * src[y * W + xx];
    }
  }
  if (accf) out[idx] += a; else out[idx] = a;
}

// ---------------- shear transforms ----------------------------------------------------------
__global__ __launch_bounds__(256) void k_htrans(const float* __restrict__ in, float* __restrict__ out) {
  int idx = blockIdx.x * 256 + threadIdx.x;
  if (idx >= 16 * 64 * 32 * 63) return;
  int j = idx % 63; int tmp = idx / 63; int i = tmp % 32; int bc = tmp / 32;
  int k = j - i;
  out[idx] = (k >= 0 && k < 32) ? in[(bc * 32 + i) * 32 + k] : 0.f;
}
__global__ __launch_bounds__(256) void k_invh_add(const float* __restrict__ F, float* __restrict__ D) {
  int idx = blockIdx.x * 256 + threadIdx.x;
  if (idx >= 16 * 64 * 1024) return;
  int j = idx % 32; int tmp = idx / 32; int i = tmp % 32; int bc = tmp / 32;
  D[idx] += F[(bc * 32 + i) * 63 + i + j];
}
__global__ __launch_bounds__(256) void k_vtrans(const float* __restrict__ in, float* __restrict__ out) {
  int idx = blockIdx.x * 256 + threadIdx.x;
  if (idx >= 16 * 64 * 63 * 32) return;
  int c = idx % 32; int tmp = idx / 32; int r = tmp % 63; int bc = tmp / 63;
  int k = r - c;
  out[idx] = (k >= 0 && k < 32) ? in[(bc * 32 + k) * 32 + c] : 0.f;
}
__global__ __launch_bounds__(256) void k_invv_add(const float* __restrict__ F, float* __restrict__ D) {
  int idx = blockIdx.x * 256 + threadIdx.x;
  if (idx >= 16 * 64 * 1024) return;
  int j = idx % 32; int tmp = idx / 32; int i = tmp % 32; int bc = tmp / 32;
  D[idx] += F[(bc * 63 + (i + j)) * 32 + j];
}

// ---------------- gate: sigmoid(bn(sum)) upsampled x3, x3_mra, xa ch128..191 ---------------
__global__ __launch_bounds__(256) void k_gate(const float* __restrict__ D, const float* __restrict__ x,
    const float* __restrict__ g, const float* __restrict__ bb,
    float* __restrict__ mra_out, bf16* __restrict__ xa) {
  int idx = blockIdx.x * 256 + threadIdx.x;
  if (idx >= 16 * 64 * 9216) return;
  int wv = idx % 96; int tmp = idx / 96; int h = tmp % 96; tmp /= 96; int c = tmp % 64; int b = tmp / 64;
  float d = D[((b * 64 + c) * 32 + h / 3) * 32 + (wv / 3)];
  float gt = sigmf(d * g[c] * BNS + bb[c]);
  float x3v = x[(b * 256 + 128 + c) * 9216 + h * 96 + wv];
  float mra = x3v * gt;
  mra_out[idx] = mra;
  xa[(b * 256 + 128 + c) * 9216 + h * 96 + wv] = __float2bfloat16(x3v + mra);
}

// ---------------- maxpool2 with argmax (first-occurrence ties) ------------------------------
__global__ __launch_bounds__(256) void k_pool2(const float* __restrict__ in, float* __restrict__ out,
                                               int* __restrict__ idxo) {
  int idx = blockIdx.x * 256 + threadIdx.x;
  if (idx >= 16 * 64 * 2304) return;
  int ow = idx % 48; int tmp = idx / 48; int oh = tmp % 48; int bc = tmp / 48;
  const float* src = in + bc * 9216;
  int y = 2 * oh, xx = 2 * ow;
  float v0 = src[y * 96 + xx], v1 = src[y * 96 + xx + 1];
  float v2 = src[(y + 1) * 96 + xx], v3 = src[(y + 1) * 96 + xx + 1];
  float best = v0; int bi = 0;
  if (v1 > best) { best = v1; bi = 1; }
  if (v2 > best) { best = v2; bi = 2; }
  if (v3 > best) { best = v3; bi = 3; }
  out[idx] = best; idxo[idx] = bi;
}

// ---------------- channel mean/max over concat(J,K) -----------------------------------------
__global__ __launch_bounds__(256) void k_agg(const float* __restrict__ J, const float* __restrict__ K,
                                             float* __restrict__ AGG) {
  int idx = blockIdx.x * 256 + threadIdx.x;
  if (idx >= 16 * 2304) return;
  int hw = idx % 2304; int b = idx / 2304;
  float sum = 0.f, mx = -3.4e38f;
  for (int j = 0; j < 32; ++j) { float v = J[(b * 32 + j) * 2304 + hw]; sum += v; mx = fmaxf(mx, v); }
  for (int j = 0; j < 32; ++j) { float v = K[(b * 32 + j) * 2304 + hw]; sum += v; mx = fmaxf(mx, v); }
  AGG[(b * 2 + 0) * 2304 + hw] = sum * (1.0f / 64.0f);
  AGG[(b * 2 + 1) * 2304 + hw] = mx;
}

// ---------------- squeeze conv 2->2 7x7 pad3 + sigmoid --------------------------------------
__global__ __launch_bounds__(256) void k_sq(const float* __restrict__ AGG, const float* __restrict__ w,
                                            const float* __restrict__ bias, float* __restrict__ SG) {
  int idx = blockIdx.x * 256 + threadIdx.x;
  if (idx >= 16 * 2 * 2304) return;
  int hw = idx % 2304; int tmp = idx / 2304; int co = tmp % 2; int b = tmp / 2;
  int h = hw / 48, wv = hw % 48;
  float acc = bias[co];
  for (int ci = 0; ci < 2; ++ci) {
    const float* src = AGG + (b * 2 + ci) * 2304;
    for (int ky = 0; ky < 7; ++ky) {
      int y = h - 3 + ky; if ((unsigned)y >= 48u) continue;
      for (int kx = 0; kx < 7; ++kx) {
        int xx = wv - 3 + kx; if ((unsigned)xx >= 48u) continue;
        acc += w[((co * 2 + ci) * 7 + ky) * 7 + kx] * src[y * 48 + xx];
      }
    }
  }
  SG[idx] = sigmf(acc);
}

__global__ __launch_bounds__(256) void k_mix(const float* __restrict__ J, const float* __restrict__ K,
                                             const float* __restrict__ SG, float* __restrict__ L) {
  int idx = blockIdx.x * 256 + threadIdx.x;
  if (idx >= 16 * 32 * 2304) return;
  int hw = idx % 2304; int tmp = idx / 2304; int b = tmp / 32;
  L[idx] = J[idx] * SG[(b * 2) * 2304 + hw] + K[idx] * SG[(b * 2 + 1) * 2304 + hw];
}

__global__ __launch_bounds__(256) void k_mul(const float* __restrict__ A, const float* __restrict__ B,
                                             float* __restrict__ O) {
  int idx = blockIdx.x * 256 + threadIdx.x;
  if (idx >= 16 * 64 * 2304) return;
  O[idx] = A[idx] * B[idx];
}

// ---------------- unpool + bn(n4), xa ch192..255 --------------------------------------------
__global__ __launch_bounds__(256) void k_unpool(const float* __restrict__ N2, const int* __restrict__ IDX,
    const float* __restrict__ x, const float* __restrict__ g, const float* __restrict__ bb,
    bf16* __restrict__ xa) {
  int idx = blockIdx.x * 256 + threadIdx.x;
  if (idx >= 16 * 64 * 9216) return;
  int wv = idx % 96; int tmp = idx / 96; int h = tmp % 96; tmp /= 96; int c = tmp % 64; int b = tmp / 64;
  int oh = h >> 1, ow = wv >> 1;
  int pos = (b * 64 + c) * 2304 + oh * 48 + ow;
  int kk = (h & 1) * 2 + (wv & 1);
  float v = (IDX[pos] == kk) ? N2[pos] : 0.f;
  float x4v = x[(b * 256 + 192 + c) * 9216 + h * 96 + wv];
  xa[(b * 256 + 192 + c) * 9216 + h * 96 + wv] =
      __float2bfloat16((x4v + v) * g[c] * BNS + bb[c]);
}

// ---------------- fused MLP 256->1024->256 + residual ---------------------------------------
__global__ __launch_bounds__(256) void k_mlp(const bf16* __restrict__ xa,
    const float* __restrict__ w1, const float* __restrict__ g1, const float* __restrict__ b1,
    const float* __restrict__ w2, const float* __restrict__ ng, const float* __restrict__ nb,
    const float* __restrict__ x, float* __restrict__ out) {
  __shared__ float xs[256][8];
  __shared__ float hs[1024][8];
  int t = threadIdx.x;
  int b = blockIdx.x / 1152;
  int hw0 = (blockIdx.x % 1152) * 8;
  for (int i = t; i < 2048; i += 256) {
    int c = i >> 3, p = i & 7;
    xs[c][p] = bf2f(xa[(b * 256 + c) * 9216 + hw0 + p]);
  }
  __syncthreads();
  for (int kk = 0; kk < 4; ++kk) {
    int k = t + 256 * kk;
    float acc[8] = {0.f, 0.f, 0.f, 0.f, 0.f, 0.f, 0.f, 0.f};
    const float* wr = w1 + k * 256;
    for (int j = 0; j < 256; ++j) {
      float wv = wr[j];
      for (int p = 0; p < 8; ++p) acc[p] += wv * xs[j][p];
    }
    float gg = g1[k] * BNS, bb = b1[k];
    for (int p = 0; p < 8; ++p) hs[k][p] = geluf(acc[p] * gg + bb);
  }
  __syncthreads();
  {
    int c = t;
    float acc[8] = {0.f, 0.f, 0.f, 0.f, 0.f, 0.f, 0.f, 0.f};
    const float* wr = w2 + c * 1024;
    for (int h = 0; h < 1024; ++h) {
      float wv = wr[h];
      for (int p = 0; p < 8; ++p) acc[p] += wv * hs[h][p];
    }
    float gg = ng[c] * BNS, bb = nb[c];
    for (int p = 0; p < 8; ++p) {
      int o = (b * 256 + c) * 9216 + hw0 + p;
      out[o] = acc[p] * gg + bb + x[o];
    }
  }
}

extern "C" void kernel_launch(void* const* d_in, const int* in_sizes, int n_in,
                              void* d_out, int out_size, void* d_ws, size_t ws_size,
                              hipStream_t stream) {
  const float* x        = (const float*)d_in[0];
  const float* pa_w1    = (const float*)d_in[1];
  const float* pa_bn_g  = (const float*)d_in[2];
  const float* pa_bn_b  = (const float*)d_in[3];
  const float* pa_w2    = (const float*)d_in[4];
  const float* fuse1_w  = (const float*)d_in[5];
  const float* la_w     = (const float*)d_in[6];
  const float* la_bn_g  = (const float*)d_in[7];
  const float* la_bn_b  = (const float*)d_in[8];
  const float* h1_w     = (const float*)d_in[9];
  const float* v1_w     = (const float*)d_in[10];
  const float* h2_w     = (const float*)d_in[11];
  const float* v2_w     = (const float*)d_in[12];
  const float* mra_bn_g = (const float*)d_in[13];
  const float* mra_bn_b = (const float*)d_in[14];
  const float* fuse2_w  = (const float*)d_in[15];
  const float* g_p1_w   = (const float*)d_in[16];
  const float* g_p1_b   = (const float*)d_in[17];
  const float* g_c0_w   = (const float*)d_in[18];
  const float* g_c0_b   = (const float*)d_in[19];
  const float* g_cs_w   = (const float*)d_in[20];
  const float* g_cs_b   = (const float*)d_in[21];
  const float* g_c1_w   = (const float*)d_in[22];
  const float* g_c1_b   = (const float*)d_in[23];
  const float* g_c2_w   = (const float*)d_in[24];
  const float* g_c2_b   = (const float*)d_in[25];
  const float* g_sq_w   = (const float*)d_in[26];
  const float* g_sq_b   = (const float*)d_in[27];
  const float* g_cv_w   = (const float*)d_in[28];
  const float* g_cv_b   = (const float*)d_in[29];
  const float* g_p2_w   = (const float*)d_in[30];
  const float* g_p2_b   = (const float*)d_in[31];
  const float* n4_g     = (const float*)d_in[32];
  const float* n4_b     = (const float*)d_in[33];
  const float* mlp_w1   = (const float*)d_in[34];
  const float* mlp_bn_g = (const float*)d_in[35];
  const float* mlp_bn_b = (const float*)d_in[36];
  const float* mlp_w2   = (const float*)d_in[37];
  const float* n1_g     = (const float*)d_in[38];
  const float* n1_b     = (const float*)d_in[39];

  // ---- compact aliased workspace: 43,974,656 floats = 175.9 MB total ----
  float* ws = (float*)d_ws;
  bf16*  XA = (bf16*)ws;                    // (16,256,96,96) bf16 = 18,874,368 float-slots
  float* P  = ws + 18874368;                // 9,437,184 f: x1pa -> maxpool3 -> mra -> GA overlay
  float* Q  = ws + 28311552;                // 9,437,184 f: fuse1-out -> fuse2-out -> GA overlay
  float* R  = ws + 37748736;                // 6,225,920 f: T/D/E/F -> J/K2/L/AGG/SG overlay
  float* T  = R;                            // 1,048,576 (16,64,32,32)
  float* D  = R + 1048576;                  // 1,048,576
  float* E  = R + 2097152;                  // 2,064,384
  float* F  = R + 4161536;                  // 2,064,384  (R total 6,225,920)
  // GA overlays (liveness-audited):
  float* C48 = P;                           // 2,359,296 (16,64,48,48)
  int*   IDX = (int*)(P + 2359296);         // 2,359,296 ints
  float* G   = P + 4718592;                 // 2,359,296
  float* H2  = P + 7077888;                 // 2,359,296  (P full)
  float* I2  = Q;                           // 2,359,296
  float* M   = Q + 2359296;                 // 2,359,296
  float* XM  = Q + 4718592;                 // 2,359,296
  float* N2  = Q + 7077888;                 // 2,359,296  (Q full)
  float* J   = R;                           // 1,179,648 (T/D/E/F dead by then)
  float* K2  = R + 1179648;                 // 1,179,648
  float* L   = R + 2359296;                 // 1,179,648
  float* AGG = R + 3538944;                 // 73,728
  float* SG  = R + 3612672;                 // 73,728

  // Branch 1 (PA) -> x1pa (P), xa ch 0..63
  k_pa<<<9216, 256, 0, stream>>>(x, pa_w1, pa_bn_g, pa_bn_b, pa_w2, P, XA);
  // Branch 2: fuse1 (x1_pa ++ x2) -> Q; la 3x3 + bn + gelu -> xa ch 64..127
  k_conv1x1<<<2304, 256, 0, stream>>>(P, 64, x, 64, 64, fuse1_w, (const float*)nullptr, 0, Q, 64, 9216);
  k_la<<<36864, 256, 0, stream>>>(Q, la_w, la_bn_g, la_bn_b, XA);
  // Branch 3 (MRA)
  k_maxpool3<<<36864, 256, 0, stream>>>(x, P);
  k_blur<<<4096, 256, 0, stream>>>(P, T);
  k_dw<<<4096, 256, 0, stream>>>(T, h1_w, (const float*)nullptr, D, 32, 32, 7, 3, 3, 1, 1, 0);
  k_dw<<<4096, 256, 0, stream>>>(T, v1_w, (const float*)nullptr, D, 32, 32, 3, 7, 1, 3, 1, 1);
  k_htrans<<<8064, 256, 0, stream>>>(T, E);
  k_dw<<<8064, 256, 0, stream>>>(E, h2_w, (const float*)nullptr, F, 32, 63, 7, 3, 3, 1, 1, 0);
  k_invh_add<<<4096, 256, 0, stream>>>(F, D);
  k_vtrans<<<8064, 256, 0, stream>>>(T, E);
  k_dw<<<8064, 256, 0, stream>>>(E, v2_w, (const float*)nullptr, F, 63, 32, 3, 7, 1, 3, 1, 0);
  k_invv_add<<<4096, 256, 0, stream>>>(F, D);
  k_gate<<<36864, 256, 0, stream>>>(D, x, mra_bn_g, mra_bn_b, P, XA);
  // Branch 4 (GA)
  k_conv1x1<<<2304, 256, 0, stream>>>(P, 64, x, 192, 64, fuse2_w, (const float*)nullptr, 0, Q, 64, 9216);
  k_pool2<<<9216, 256, 0, stream>>>(Q, C48, IDX);
  k_conv1x1<<<576, 256, 0, stream>>>(C48, 64, (const float*)nullptr, 0, 0, g_p1_w, g_p1_b, 1, G, 64, 2304);
  k_dw<<<9216, 256, 0, stream>>>(G, g_c0_w, g_c0_b, H2, 48, 48, 5, 5, 2, 2, 1, 0);
  k_dw<<<9216, 256, 0, stream>>>(H2, g_cs_w, g_cs_b, I2, 48, 48, 7, 7, 9, 9, 3, 0);
  k_conv1x1<<<576, 256, 0, stream>>>(H2, 64, (const float*)nullptr, 0, 0, g_c1_w, g_c1_b, 0, J, 32, 2304);
  k_conv1x1<<<576, 256, 0, stream>>>(I2, 64, (const float*)nullptr, 0, 0, g_c2_w, g_c2_b, 0, K2, 32, 2304);
  k_agg<<<144, 256, 0, stream>>>(J, K2, AGG);
  k_sq<<<288, 256, 0, stream>>>(AGG, g_sq_w, g_sq_b, SG);
  k_mix<<<4608, 256, 0, stream>>>(J, K2, SG, L);
  k_conv1x1<<<576, 256, 0, stream>>>(L, 32, (const float*)nullptr, 0, 0, g_cv_w, g_cv_b, 0, M, 64, 2304);
  k_mul<<<9216, 256, 0, stream>>>(G, M, XM);
  k_conv1x1<<<576, 256, 0, stream>>>(XM, 64, (const float*)nullptr, 0, 0, g_p2_w, g_p2_b, 0, N2, 64, 2304);
  k_unpool<<<36864, 256, 0, stream>>>(N2, IDX, x, n4_g, n4_b, XA);
  // MLP + residual
  k_mlp<<<18432, 256, 0, stream>>>(XA, mlp_w1, mlp_bn_g, mlp_bn_b, mlp_w2, n1_g, n1_b, x, (float*)d_out);
}

// Round 4
// 4001.825 us; speedup vs baseline: 1.8346x; 1.8346x over previous
//
#include <hip/hip_runtime.h>
#include <hip/hip_bf16.h>

typedef __hip_bfloat16 bf16;
typedef short bf16x8 __attribute__((ext_vector_type(8)));
typedef float f32x4 __attribute__((ext_vector_type(4)));

#define BNS 0.9999950000374997f  /* 1/sqrt(1+1e-5) */

__device__ __forceinline__ float bf2f(bf16 v) { return __bfloat162float(v); }
__device__ __forceinline__ float geluf(float x) { return 0.5f * x * (1.0f + erff(x * 0.70710678118654752f)); }
__device__ __forceinline__ float sigmf(float x) { return 1.0f / (1.0f + expf(-x)); }
__device__ __forceinline__ unsigned short f2b(float f) { bf16 h = __float2bfloat16(f); return *(unsigned short*)&h; }

// ---------------- PA branch: fused 1x1(64->256)+bn+gelu+1x1(256->64)+sigmoid gate ----------
__global__ __launch_bounds__(256) void k_pa(const float* __restrict__ x,
    const float* __restrict__ w1, const float* __restrict__ g1, const float* __restrict__ b1,
    const float* __restrict__ w2, float* __restrict__ x1pa, bf16* __restrict__ xa) {
  __shared__ float xs[16][65];
  __shared__ float hs[16][257];
  int t = threadIdx.x;
  int b = blockIdx.x / 576;
  int hw0 = (blockIdx.x % 576) * 16;
  for (int i = t; i < 16 * 64; i += 256) {
    int p = i >> 6, c = i & 63;
    xs[p][c] = x[(b * 256 + c) * 9216 + hw0 + p];
  }
  __syncthreads();
  {
    int k = t;
    float gg = g1[k] * BNS, bb = b1[k];
    const float* wr = w1 + k * 64;
    for (int p = 0; p < 16; ++p) {
      float acc = 0.f;
      for (int j = 0; j < 64; ++j) acc += wr[j] * xs[p][j];
      hs[p][k] = geluf(acc * gg + bb);
    }
  }
  __syncthreads();
  for (int i = t; i < 16 * 64; i += 256) {
    int p = i & 15, c = i >> 4;
    float acc = 0.f;
    const float* wr = w2 + c * 256;
    for (int k = 0; k < 256; ++k) acc += wr[k] * hs[p][k];
    float x1v = xs[p][c];
    float pa = x1v * sigmf(acc);
    x1pa[(b * 64 + c) * 9216 + hw0 + p] = pa;
    xa[(b * 256 + c) * 9216 + hw0 + p] = __float2bfloat16(x1v + pa);
  }
}

// ---------------- generic 1x1 conv: inA (fp32, CinA ch) [+ x slice (fp32, CinB ch)] --------
__global__ __launch_bounds__(256) void k_conv1x1(const float* __restrict__ inA, int CinA,
    const float* __restrict__ xsrc, int xoff, int CinB,
    const float* __restrict__ w, const float* __restrict__ bias, int act,
    float* __restrict__ out, int Cout, int npix) {
  __shared__ float s[128][64];
  int t = threadIdx.x;
  int p0 = blockIdx.x * 64;
  int b = p0 / npix;
  int hw0 = p0 % npix;
  int Cin = CinA + CinB;
  for (int i = t; i < Cin * 64; i += 256) {
    int cch = i >> 6, p = i & 63;
    float v;
    if (cch < CinA) v = inA[(b * CinA + cch) * npix + hw0 + p];
    else v = xsrc[(b * 256 + xoff + (cch - CinA)) * 9216 + hw0 + p];
    s[cch][p] = v;
  }
  __syncthreads();
  int px = t & 63;
  for (int c = (t >> 6); c < Cout; c += 4) {
    float acc = bias ? bias[c] : 0.0f;
    const float* wr = w + c * Cin;
    for (int j = 0; j < Cin; ++j) acc += wr[j] * s[j][px];
    if (act == 1) acc = geluf(acc);
    out[(b * Cout + c) * npix + hw0 + px] = acc;
  }
}

// ---------------- la: 3x3 conv 64->64 pad1 + bn + gelu, writes xa channels 64..127 ---------
__global__ __launch_bounds__(256) void k_la(const float* __restrict__ in,
    const float* __restrict__ w, const float* __restrict__ g, const float* __restrict__ bb,
    bf16* __restrict__ xa) {
  int bid = blockIdx.x;
  int tile = bid % 36; int co = (bid / 36) % 64; int b = bid / (36 * 64);
  int th0 = (tile / 6) * 16, tw0 = (tile % 6) * 16;
  int t = threadIdx.x; int ty = t >> 4, tx = t & 15;
  __shared__ float s[18][18];
  float acc = 0.f;
  for (int ci = 0; ci < 64; ++ci) {
    __syncthreads();
    for (int i = t; i < 18 * 18; i += 256) {
      int iy = i / 18, ix = i % 18;
      int y = th0 - 1 + iy, xx = tw0 - 1 + ix;
      float v = 0.f;
      if (y >= 0 && y < 96 && xx >= 0 && xx < 96) v = in[(b * 64 + ci) * 9216 + y * 96 + xx];
      s[iy][ix] = v;
    }
    __syncthreads();
    const float* wr = w + (co * 64 + ci) * 9;
    for (int ky = 0; ky < 3; ++ky)
      for (int kx = 0; kx < 3; ++kx)
        acc += wr[ky * 3 + kx] * s[ty + ky][tx + kx];
  }
  float r = geluf(acc * (g[co] * BNS) + bb[co]);
  xa[(b * 256 + 64 + co) * 9216 + (th0 + ty) * 96 + (tw0 + tx)] = __float2bfloat16(r);
}

// ---------------- maxpool3 (3x3, stride1, pad1, -inf) on x3 -> fp32 -------------------------
__global__ __launch_bounds__(256) void k_maxpool3(const float* __restrict__ x, float* __restrict__ out) {
  int idx = blockIdx.x * 256 + threadIdx.x;
  if (idx >= 16 * 64 * 9216) return;
  int wpx = idx % 96; int tmp = idx / 96; int h = tmp % 96; tmp /= 96; int c = tmp % 64; int b = tmp / 64;
  const float* src = x + (b * 256 + 128 + c) * 9216;
  float m = -3.4e38f;
  for (int dy = -1; dy <= 1; ++dy) {
    int y = h + dy; if ((unsigned)y >= 96u) continue;
    for (int dx = -1; dx <= 1; ++dx) {
      int xx = wpx + dx; if ((unsigned)xx >= 96u) continue;
      m = fmaxf(m, src[y * 96 + xx]);
    }
  }
  out[idx] = m;
}

// ---------------- blurpool: reflect pad (1,2), 4x4 blur, stride 3: 96->32 ------------------
__global__ __launch_bounds__(256) void k_blur(const float* __restrict__ in, float* __restrict__ out) {
  int idx = blockIdx.x * 256 + threadIdx.x;
  if (idx >= 16 * 64 * 1024) return;
  int ow = idx % 32; int tmp = idx / 32; int oh = tmp % 32; int bc = tmp / 32;
  const float* src = in + bc * 9216;
  const float a4[4] = {1.f, 3.f, 3.f, 1.f};
  float s = 0.f;
  for (int ky = 0; ky < 4; ++ky) {
    int sy = 3 * oh + ky - 1; if (sy < 0) sy = -sy; if (sy > 95) sy = 190 - sy;
    for (int kx = 0; kx < 4; ++kx) {
      int sx = 3 * ow + kx - 1; if (sx < 0) sx = -sx; if (sx > 95) sx = 190 - sx;
      s += a4[ky] * a4[kx] * src[sy * 96 + sx];
    }
  }
  out[idx] = s * (1.0f / 64.0f);
}

// ---------------- generic depthwise conv (B=16, C=64) --------------------------------------
__global__ __launch_bounds__(256) void k_dw(const float* __restrict__ in, const float* __restrict__ w,
    const float* __restrict__ bias, float* __restrict__ out,
    int H, int W, int KH, int KW, int pH, int pW, int dil, int accf) {
  int idx = blockIdx.x * 256 + threadIdx.x;
  int total = 16 * 64 * H * W; if (idx >= total) return;
  int wpx = idx % W; int tmp = idx / W; int h = tmp % H; tmp /= H; int c = tmp % 64;
  const float* src = in + tmp * H * W;
  const float* wr = w + c * KH * KW;
  float a = bias ? bias[c] : 0.f;
  for (int ky = 0; ky < KH; ++ky) {
    int y = h - pH + ky * dil; if ((unsigned)y >= (unsigned)H) continue;
    for (int kx = 0; kx < KW; ++kx) {
      int xx = wpx - pW + kx * dil; if ((unsigned)xx >= (unsigned)W) continue;
      a += wr[ky * KW + kx] * src[y * W + xx];
    }
  }
  if (accf) out[idx] += a; else out[idx] = a;
}

// ---------------- shear transforms ----------------------------------------------------------
__global__ __launch_bounds__(256) void k_htrans(const float* __restrict__ in, float* __restrict__ out) {
  int idx = blockIdx.x * 256 + threadIdx.x;
  if (idx >= 16 * 64 * 32 * 63) return;
  int j = idx % 63; int tmp = idx / 63; int i = tmp % 32; int bc = tmp / 32;
  int k = j - i;
  out[idx] = (k >= 0 && k < 32) ? in[(bc * 32 + i) * 32 + k] : 0.f;
}
__global__ __launch_bounds__(256) void k_invh_add(const float* __restrict__ F, float* __restrict__ D) {
  int idx = blockIdx.x * 256 + threadIdx.x;
  if (idx >= 16 * 64 * 1024) return;
  int j = idx % 32; int tmp = idx / 32; int i = tmp % 32; int bc = tmp / 32;
  D[idx] += F[(bc * 32 + i) * 63 + i + j];
}
__global__ __launch_bounds__(256) void k_vtrans(const float* __restrict__ in, float* __restrict__ out) {
  int idx = blockIdx.x * 256 + threadIdx.x;
  if (idx >= 16 * 64 * 63 * 32) return;
  int c = idx % 32; int tmp = idx / 32; int r = tmp % 63; int bc = tmp / 63;
  int k = r - c;
  out[idx] = (k >= 0 && k < 32) ? in[(bc * 32 + k) * 32 + c] : 0.f;
}
__global__ __launch_bounds__(256) void k_invv_add(const float* __restrict__ F, float* __restrict__ D) {
  int idx = blockIdx.x * 256 + threadIdx.x;
  if (idx >= 16 * 64 * 1024) return;
  int j = idx % 32; int tmp = idx / 32; int i = tmp % 32; int bc = tmp / 32;
  D[idx] += F[(bc * 63 + (i + j)) * 32 + j];
}

// ---------------- gate: sigmoid(bn(sum)) upsampled x3, x3_mra, xa ch128..191 ---------------
__global__ __launch_bounds__(256) void k_gate(const float* __restrict__ D, const float* __restrict__ x,
    const float* __restrict__ g, const float* __restrict__ bb,
    float* __restrict__ mra_out, bf16* __restrict__ xa) {
  int idx = blockIdx.x * 256 + threadIdx.x;
  if (idx >= 16 * 64 * 9216) return;
  int wv = idx % 96; int tmp = idx / 96; int h = tmp % 96; tmp /= 96; int c = tmp % 64; int b = tmp / 64;
  float d = D[((b * 64 + c) * 32 + h / 3) * 32 + (wv / 3)];
  float gt = sigmf(d * g[c] * BNS + bb[c]);
  float x3v = x[(b * 256 + 128 + c) * 9216 + h * 96 + wv];
  float mra = x3v * gt;
  mra_out[idx] = mra;
  xa[(b * 256 + 128 + c) * 9216 + h * 96 + wv] = __float2bfloat16(x3v + mra);
}

// ---------------- maxpool2 with argmax (first-occurrence ties) ------------------------------
__global__ __launch_bounds__(256) void k_pool2(const float* __restrict__ in, float* __restrict__ out,
                                               int* __restrict__ idxo) {
  int idx = blockIdx.x * 256 + threadIdx.x;
  if (idx >= 16 * 64 * 2304) return;
  int ow = idx % 48; int tmp = idx / 48; int oh = tmp % 48; int bc = tmp / 48;
  const float* src = in + bc * 9216;
  int y = 2 * oh, xx = 2 * ow;
  float v0 = src[y * 96 + xx], v1 = src[y * 96 + xx + 1];
  float v2 = src[(y + 1) * 96 + xx], v3 = src[(y + 1) * 96 + xx + 1];
  float best = v0; int bi = 0;
  if (v1 > best) { best = v1; bi = 1; }
  if (v2 > best) { best = v2; bi = 2; }
  if (v3 > best) { best = v3; bi = 3; }
  out[idx] = best; idxo[idx] = bi;
}

// ---------------- channel mean/max over concat(J,K) -----------------------------------------
__global__ __launch_bounds__(256) void k_agg(const float* __restrict__ J, const float* __restrict__ K,
                                             float* __restrict__ AGG) {
  int idx = blockIdx.x * 256 + threadIdx.x;
  if (idx >= 16 * 2304) return;
  int hw = idx % 2304; int b = idx / 2304;
  float sum = 0.f, mx = -3.4e38f;
  for (int j = 0; j < 32; ++j) { float v = J[(b * 32 + j) * 2304 + hw]; sum += v; mx = fmaxf(mx, v); }
  for (int j = 0; j < 32; ++j) { float v = K[(b * 32 + j) * 2304 + hw]; sum += v; mx = fmaxf(mx, v); }
  AGG[(b * 2 + 0) * 2304 + hw] = sum * (1.0f / 64.0f);
  AGG[(b * 2 + 1) * 2304 + hw] = mx;
}

// ---------------- squeeze conv 2->2 7x7 pad3 + sigmoid --------------------------------------
__global__ __launch_bounds__(256) void k_sq(const float* __restrict__ AGG, const float* __restrict__ w,
                                            const float* __restrict__ bias, float* __restrict__ SG) {
  int idx = blockIdx.x * 256 + threadIdx.x;
  if (idx >= 16 * 2 * 2304) return;
  int hw = idx % 2304; int tmp = idx / 2304; int co = tmp % 2; int b = tmp / 2;
  int h = hw / 48, wv = hw % 48;
  float acc = bias[co];
  for (int ci = 0; ci < 2; ++ci) {
    const float* src = AGG + (b * 2 + ci) * 2304;
    for (int ky = 0; ky < 7; ++ky) {
      int y = h - 3 + ky; if ((unsigned)y >= 48u) continue;
      for (int kx = 0; kx < 7; ++kx) {
        int xx = wv - 3 + kx; if ((unsigned)xx >= 48u) continue;
        acc += w[((co * 2 + ci) * 7 + ky) * 7 + kx] * src[y * 48 + xx];
      }
    }
  }
  SG[idx] = sigmf(acc);
}

__global__ __launch_bounds__(256) void k_mix(const float* __restrict__ J, const float* __restrict__ K,
                                             const float* __restrict__ SG, float* __restrict__ L) {
  int idx = blockIdx.x * 256 + threadIdx.x;
  if (idx >= 16 * 32 * 2304) return;
  int hw = idx % 2304; int tmp = idx / 2304; int b = tmp / 32;
  L[idx] = J[idx] * SG[(b * 2) * 2304 + hw] + K[idx] * SG[(b * 2 + 1) * 2304 + hw];
}

__global__ __launch_bounds__(256) void k_mul(const float* __restrict__ A, const float* __restrict__ B,
                                             float* __restrict__ O) {
  int idx = blockIdx.x * 256 + threadIdx.x;
  if (idx >= 16 * 64 * 2304) return;
  O[idx] = A[idx] * B[idx];
}

// ---------------- unpool + bn(n4), xa ch192..255 --------------------------------------------
__global__ __launch_bounds__(256) void k_unpool(const float* __restrict__ N2, const int* __restrict__ IDX,
    const float* __restrict__ x, const float* __restrict__ g, const float* __restrict__ bb,
    bf16* __restrict__ xa) {
  int idx = blockIdx.x * 256 + threadIdx.x;
  if (idx >= 16 * 64 * 9216) return;
  int wv = idx % 96; int tmp = idx / 96; int h = tmp % 96; tmp /= 96; int c = tmp % 64; int b = tmp / 64;
  int oh = h >> 1, ow = wv >> 1;
  int pos = (b * 64 + c) * 2304 + oh * 48 + ow;
  int kk = (h & 1) * 2 + (wv & 1);
  float v = (IDX[pos] == kk) ? N2[pos] : 0.f;
  float x4v = x[(b * 256 + 192 + c) * 9216 + h * 96 + wv];
  xa[(b * 256 + 192 + c) * 9216 + h * 96 + wv] =
      __float2bfloat16((x4v + v) * g[c] * BNS + bb[c]);
}

// ---------------- prep: fp32 weights -> bf16 with BN scale folded ---------------------------
__global__ __launch_bounds__(256) void k_prep(const float* __restrict__ w1, const float* __restrict__ g1,
    const float* __restrict__ w2, const float* __restrict__ ng,
    unsigned short* __restrict__ w1b, unsigned short* __restrict__ w2b) {
  int i = blockIdx.x * 256 + threadIdx.x;
  if (i < 262144) {
    w1b[i] = f2b(w1[i] * (g1[i >> 8] * BNS));
    w2b[i] = f2b(w2[i] * (ng[i >> 10] * BNS));
  }
}

// ---------------- fused MFMA MLP: 256->1024(gelu)->256 + residual ---------------------------
// per block: 64 pixels; 4 waves, wave w owns pixels [w*16, w*16+16).
// GEMM1 A=W1B (global frags), B=xs (LDS). H chunk(64) -> gelu -> hs (wave-private LDS rows).
// GEMM2 A=W2B (global frags), B=hs. Y acc 256x16 per wave in 16 f32x4 frags.
__global__ __launch_bounds__(256) void k_mlp_mfma(
    const unsigned short* __restrict__ XA,
    const unsigned short* __restrict__ W1B, const float* __restrict__ b1,
    const unsigned short* __restrict__ W2B, const float* __restrict__ nbv,
    const float* __restrict__ xin, float* __restrict__ out) {
  __shared__ unsigned short xs[64][264];   // [pixel][cin], +8 pad: 2-way conflicts only
  __shared__ unsigned short hs[64][72];    // [pixel][hidden_local], wave-private rows
  __shared__ float b1s[1024];
  __shared__ float nbs[256];
  int t = threadIdx.x;
  int b = blockIdx.x / 144;
  int hw0 = (blockIdx.x % 144) * 64;
  for (int i = t; i < 1024; i += 256) b1s[i] = b1[i];
  if (t < 256) nbs[t] = nbv[t];
  {
    int p = t & 63; int cq = t >> 6;
    const unsigned short* src = XA + (size_t)(b * 256) * 9216 + hw0 + p;
    for (int c = cq * 2; c < 256; c += 8) {
      unsigned lo = src[(size_t)c * 9216];
      unsigned hi = src[(size_t)(c + 1) * 9216];
      *(unsigned*)&xs[p][c] = lo | (hi << 16);
    }
  }
  __syncthreads();
  int lane = t & 63, wave = t >> 6;
  int n0 = wave * 16;
  int lm = lane & 15, lk = lane >> 4;
  f32x4 Y[16];
#pragma unroll
  for (int i = 0; i < 16; ++i) Y[i] = (f32x4){0.f, 0.f, 0.f, 0.f};
  const unsigned short* xr = &xs[n0 + lm][lk * 8];
  const unsigned short* hr = &hs[n0 + lm][lk * 8];
  for (int chunk = 0; chunk < 16; ++chunk) {
    int h0 = chunk * 64;
    f32x4 Hc[4];
#pragma unroll
    for (int mh = 0; mh < 4; ++mh) Hc[mh] = (f32x4){0.f, 0.f, 0.f, 0.f};
#pragma unroll
    for (int k = 0; k < 256; k += 32) {
      bf16x8 bfrag = *(const bf16x8*)(xr + k);
#pragma unroll
      for (int mh = 0; mh < 4; ++mh) {
        bf16x8 afrag = *(const bf16x8*)&W1B[(size_t)(h0 + mh * 16 + lm) * 256 + k + lk * 8];
        Hc[mh] = __builtin_amdgcn_mfma_f32_16x16x32_bf16(afrag, bfrag, Hc[mh], 0, 0, 0);
      }
    }
#pragma unroll
    for (int mh = 0; mh < 4; ++mh) {
#pragma unroll
      for (int r = 0; r < 4; r += 2) {
        int hrl = mh * 16 + lk * 4 + r;          // hidden index within chunk? no: within M-block
        int hrow = h0 + hrl;
        float v0 = geluf(Hc[mh][r]     + b1s[hrow]);
        float v1 = geluf(Hc[mh][r + 1] + b1s[hrow + 1]);
        unsigned u = (unsigned)f2b(v0) | ((unsigned)f2b(v1) << 16);
        *(unsigned*)&hs[n0 + lm][hrl] = u;
      }
    }
#pragma unroll
    for (int k = 0; k < 64; k += 32) {
      bf16x8 bfrag = *(const bf16x8*)(hr + k);
#pragma unroll
      for (int mt = 0; mt < 16; ++mt) {
        bf16x8 afrag = *(const bf16x8*)&W2B[(size_t)(mt * 16 + lm) * 1024 + h0 + k + lk * 8];
        Y[mt] = __builtin_amdgcn_mfma_f32_16x16x32_bf16(afrag, bfrag, Y[mt], 0, 0, 0);
      }
    }
  }
#pragma unroll
  for (int mt = 0; mt < 16; ++mt) {
#pragma unroll
    for (int r = 0; r < 4; ++r) {
      int m = mt * 16 + lk * 4 + r;
      size_t o = (size_t)(b * 256 + m) * 9216 + hw0 + n0 + lm;
      out[o] = Y[mt][r] + nbs[m] + xin[o];
    }
  }
}

extern "C" void kernel_launch(void* const* d_in, const int* in_sizes, int n_in,
                              void* d_out, int out_size, void* d_ws, size_t ws_size,
                              hipStream_t stream) {
  const float* x        = (const float*)d_in[0];
  const float* pa_w1    = (const float*)d_in[1];
  const float* pa_bn_g  = (const float*)d_in[2];
  const float* pa_bn_b  = (const float*)d_in[3];
  const float* pa_w2    = (const float*)d_in[4];
  const float* fuse1_w  = (const float*)d_in[5];
  const float* la_w     = (const float*)d_in[6];
  const float* la_bn_g  = (const float*)d_in[7];
  const float* la_bn_b  = (const float*)d_in[8];
  const float* h1_w     = (const float*)d_in[9];
  const float* v1_w     = (const float*)d_in[10];
  const float* h2_w     = (const float*)d_in[11];
  const float* v2_w     = (const float*)d_in[12];
  const float* mra_bn_g = (const float*)d_in[13];
  const float* mra_bn_b = (const float*)d_in[14];
  const float* fuse2_w  = (const float*)d_in[15];
  const float* g_p1_w   = (const float*)d_in[16];
  const float* g_p1_b   = (const float*)d_in[17];
  const float* g_c0_w   = (const float*)d_in[18];
  const float* g_c0_b   = (const float*)d_in[19];
  const float* g_cs_w   = (const float*)d_in[20];
  const float* g_cs_b   = (const float*)d_in[21];
  const float* g_c1_w   = (const float*)d_in[22];
  const float* g_c1_b   = (const float*)d_in[23];
  const float* g_c2_w   = (const float*)d_in[24];
  const float* g_c2_b   = (const float*)d_in[25];
  const float* g_sq_w   = (const float*)d_in[26];
  const float* g_sq_b   = (const float*)d_in[27];
  const float* g_cv_w   = (const float*)d_in[28];
  const float* g_cv_b   = (const float*)d_in[29];
  const float* g_p2_w   = (const float*)d_in[30];
  const float* g_p2_b   = (const float*)d_in[31];
  const float* n4_g     = (const float*)d_in[32];
  const float* n4_b     = (const float*)d_in[33];
  const float* mlp_w1   = (const float*)d_in[34];
  const float* mlp_bn_g = (const float*)d_in[35];
  const float* mlp_bn_b = (const float*)d_in[36];
  const float* mlp_w2   = (const float*)d_in[37];
  const float* n1_g     = (const float*)d_in[38];
  const float* n1_b     = (const float*)d_in[39];

  // ---- compact aliased workspace: 44,236,800 floats = 176.9 MB total ----
  float* ws = (float*)d_ws;
  bf16*  XA = (bf16*)ws;                    // (16,256,96,96) bf16 = 18,874,368 float-slots
  float* P  = ws + 18874368;                // 9,437,184 f
  float* Q  = ws + 28311552;                // 9,437,184 f
  float* R  = ws + 37748736;                // 6,225,920 f
  float* T  = R;                            // 1,048,576 (16,64,32,32)
  float* D  = R + 1048576;
  float* E  = R + 2097152;                  // 2,064,384
  float* F  = R + 4161536;                  // 2,064,384
  float* C48 = P;                           // 2,359,296 (16,64,48,48)
  int*   IDX = (int*)(P + 2359296);
  float* G   = P + 4718592;
  float* H2  = P + 7077888;
  float* I2  = Q;
  float* M   = Q + 2359296;
  float* XM  = Q + 4718592;
  float* N2  = Q + 7077888;
  float* J   = R;
  float* K2  = R + 1179648;
  float* L   = R + 2359296;
  float* AGG = R + 3538944;
  float* SG  = R + 3612672;
  unsigned short* W1B = (unsigned short*)(ws + 43974656);  // 262144 bf16 (512 KB)
  unsigned short* W2B = (unsigned short*)(ws + 43974656 + 131072);

  // Prep (independent): bf16 weights with folded BN scales
  k_prep<<<1024, 256, 0, stream>>>(mlp_w1, mlp_bn_g, mlp_w2, n1_g, W1B, W2B);
  // Branch 1 (PA) -> x1pa (P), xa ch 0..63
  k_pa<<<9216, 256, 0, stream>>>(x, pa_w1, pa_bn_g, pa_bn_b, pa_w2, P, XA);
  // Branch 2: fuse1 (x1_pa ++ x2) -> Q; la 3x3 + bn + gelu -> xa ch 64..127
  k_conv1x1<<<2304, 256, 0, stream>>>(P, 64, x, 64, 64, fuse1_w, (const float*)nullptr, 0, Q, 64, 9216);
  k_la<<<36864, 256, 0, stream>>>(Q, la_w, la_bn_g, la_bn_b, XA);
  // Branch 3 (MRA)
  k_maxpool3<<<36864, 256, 0, stream>>>(x, P);
  k_blur<<<4096, 256, 0, stream>>>(P, T);
  k_dw<<<4096, 256, 0, stream>>>(T, h1_w, (const float*)nullptr, D, 32, 32, 7, 3, 3, 1, 1, 0);
  k_dw<<<4096, 256, 0, stream>>>(T, v1_w, (const float*)nullptr, D, 32, 32, 3, 7, 1, 3, 1, 1);
  k_htrans<<<8064, 256, 0, stream>>>(T, E);
  k_dw<<<8064, 256, 0, stream>>>(E, h2_w, (const float*)nullptr, F, 32, 63, 7, 3, 3, 1, 1, 0);
  k_invh_add<<<4096, 256, 0, stream>>>(F, D);
  k_vtrans<<<8064, 256, 0, stream>>>(T, E);
  k_dw<<<8064, 256, 0, stream>>>(E, v2_w, (const float*)nullptr, F, 63, 32, 3, 7, 1, 3, 1, 0);
  k_invv_add<<<4096, 256, 0, stream>>>(F, D);
  k_gate<<<36864, 256, 0, stream>>>(D, x, mra_bn_g, mra_bn_b, P, XA);
  // Branch 4 (GA)
  k_conv1x1<<<2304, 256, 0, stream>>>(P, 64, x, 192, 64, fuse2_w, (const float*)nullptr, 0, Q, 64, 9216);
  k_pool2<<<9216, 256, 0, stream>>>(Q, C48, IDX);
  k_conv1x1<<<576, 256, 0, stream>>>(C48, 64, (const float*)nullptr, 0, 0, g_p1_w, g_p1_b, 1, G, 64, 2304);
  k_dw<<<9216, 256, 0, stream>>>(G, g_c0_w, g_c0_b, H2, 48, 48, 5, 5, 2, 2, 1, 0);
  k_dw<<<9216, 256, 0, stream>>>(H2, g_cs_w, g_cs_b, I2, 48, 48, 7, 7, 9, 9, 3, 0);
  k_conv1x1<<<576, 256, 0, stream>>>(H2, 64, (const float*)nullptr, 0, 0, g_c1_w, g_c1_b, 0, J, 32, 2304);
  k_conv1x1<<<576, 256, 0, stream>>>(I2, 64, (const float*)nullptr, 0, 0, g_c2_w, g_c2_b, 0, K2, 32, 2304);
  k_agg<<<144, 256, 0, stream>>>(J, K2, AGG);
  k_sq<<<288, 256, 0, stream>>>(AGG, g_sq_w, g_sq_b, SG);
  k_mix<<<4608, 256, 0, stream>>>(J, K2, SG, L);
  k_conv1x1<<<576, 256, 0, stream>>>(L, 32, (const float*)nullptr, 0, 0, g_cv_w, g_cv_b, 0, M, 64, 2304);
  k_mul<<<9216, 256, 0, stream>>>(G, M, XM);
  k_conv1x1<<<576, 256, 0, stream>>>(XM, 64, (const float*)nullptr, 0, 0, g_p2_w, g_p2_b, 0, N2, 64, 2304);
  k_unpool<<<36864, 256, 0, stream>>>(N2, IDX, x, n4_g, n4_b, XA);
  // MLP + residual (MFMA)
  k_mlp_mfma<<<2304, 256, 0, stream>>>((const unsigned short*)XA, W1B, mlp_bn_b, W2B, n1_b,
                                       x, (float*)d_out);
}

// Round 5
// 2826.999 us; speedup vs baseline: 2.5970x; 1.4156x over previous
//
#include <hip/hip_runtime.h>
#include <hip/hip_bf16.h>

typedef __hip_bfloat16 bf16;
typedef short bf16x8 __attribute__((ext_vector_type(8)));
typedef float f32x4 __attribute__((ext_vector_type(4)));

#define BNS 0.9999950000374997f  /* 1/sqrt(1+1e-5) */

__device__ __forceinline__ float bf2f(bf16 v) { return __bfloat162float(v); }
__device__ __forceinline__ float geluf(float x) { return 0.5f * x * (1.0f + erff(x * 0.70710678118654752f)); }
__device__ __forceinline__ float sigmf(float x) { return 1.0f / (1.0f + expf(-x)); }
__device__ __forceinline__ unsigned short f2b(float f) { bf16 h = __float2bfloat16(f); return *(unsigned short*)&h; }

// ---------------- PA branch: fused 1x1(64->256)+bn+gelu+1x1(256->64)+sigmoid gate ----------
__global__ __launch_bounds__(256) void k_pa(const float* __restrict__ x,
    const float* __restrict__ w1, const float* __restrict__ g1, const float* __restrict__ b1,
    const float* __restrict__ w2, float* __restrict__ x1pa, bf16* __restrict__ xa) {
  __shared__ float xs[16][65];
  __shared__ float hs[16][257];
  int t = threadIdx.x;
  int b = blockIdx.x / 576;
  int hw0 = (blockIdx.x % 576) * 16;
  for (int i = t; i < 16 * 64; i += 256) {
    int p = i >> 6, c = i & 63;
    xs[p][c] = x[(b * 256 + c) * 9216 + hw0 + p];
  }
  __syncthreads();
  {
    int k = t;
    float gg = g1[k] * BNS, bb = b1[k];
    const float* wr = w1 + k * 64;
    for (int p = 0; p < 16; ++p) {
      float acc = 0.f;
      for (int j = 0; j < 64; ++j) acc += wr[j] * xs[p][j];
      hs[p][k] = geluf(acc * gg + bb);
    }
  }
  __syncthreads();
  for (int i = t; i < 16 * 64; i += 256) {
    int p = i & 15, c = i >> 4;
    float acc = 0.f;
    const float* wr = w2 + c * 256;
    for (int k = 0; k < 256; ++k) acc += wr[k] * hs[p][k];
    float x1v = xs[p][c];
    float pa = x1v * sigmf(acc);
    x1pa[(b * 64 + c) * 9216 + hw0 + p] = pa;
    xa[(b * 256 + c) * 9216 + hw0 + p] = __float2bfloat16(x1v + pa);
  }
}

// ---------------- generic 1x1 conv ----------------------------------------------------------
__global__ __launch_bounds__(256) void k_conv1x1(const float* __restrict__ inA, int CinA,
    const float* __restrict__ xsrc, int xoff, int CinB,
    const float* __restrict__ w, const float* __restrict__ bias, int act,
    float* __restrict__ out, int Cout, int npix) {
  __shared__ float s[128][64];
  int t = threadIdx.x;
  int p0 = blockIdx.x * 64;
  int b = p0 / npix;
  int hw0 = p0 % npix;
  int Cin = CinA + CinB;
  for (int i = t; i < Cin * 64; i += 256) {
    int cch = i >> 6, p = i & 63;
    float v;
    if (cch < CinA) v = inA[(b * CinA + cch) * npix + hw0 + p];
    else v = xsrc[(b * 256 + xoff + (cch - CinA)) * 9216 + hw0 + p];
    s[cch][p] = v;
  }
  __syncthreads();
  int px = t & 63;
  for (int c = (t >> 6); c < Cout; c += 4) {
    float acc = bias ? bias[c] : 0.0f;
    const float* wr = w + c * Cin;
    for (int j = 0; j < Cin; ++j) acc += wr[j] * s[j][px];
    if (act == 1) acc = geluf(acc);
    out[(b * Cout + c) * npix + hw0 + px] = acc;
  }
}

// ---------------- la: 3x3 conv 64->64 pad1 + bn + gelu, writes xa channels 64..127 ---------
__global__ __launch_bounds__(256) void k_la(const float* __restrict__ in,
    const float* __restrict__ w, const float* __restrict__ g, const float* __restrict__ bb,
    bf16* __restrict__ xa) {
  int bid = blockIdx.x;
  int tile = bid % 36; int co = (bid / 36) % 64; int b = bid / (36 * 64);
  int th0 = (tile / 6) * 16, tw0 = (tile % 6) * 16;
  int t = threadIdx.x; int ty = t >> 4, tx = t & 15;
  __shared__ float s[18][18];
  float acc = 0.f;
  for (int ci = 0; ci < 64; ++ci) {
    __syncthreads();
    for (int i = t; i < 18 * 18; i += 256) {
      int iy = i / 18, ix = i % 18;
      int y = th0 - 1 + iy, xx = tw0 - 1 + ix;
      float v = 0.f;
      if (y >= 0 && y < 96 && xx >= 0 && xx < 96) v = in[(b * 64 + ci) * 9216 + y * 96 + xx];
      s[iy][ix] = v;
    }
    __syncthreads();
    const float* wr = w + (co * 64 + ci) * 9;
    for (int ky = 0; ky < 3; ++ky)
      for (int kx = 0; kx < 3; ++kx)
        acc += wr[ky * 3 + kx] * s[ty + ky][tx + kx];
  }
  float r = geluf(acc * (g[co] * BNS) + bb[co]);
  xa[(b * 256 + 64 + co) * 9216 + (th0 + ty) * 96 + (tw0 + tx)] = __float2bfloat16(r);
}

// ---------------- maxpool3 -------------------------------------------------------------------
__global__ __launch_bounds__(256) void k_maxpool3(const float* __restrict__ x, float* __restrict__ out) {
  int idx = blockIdx.x * 256 + threadIdx.x;
  if (idx >= 16 * 64 * 9216) return;
  int wpx = idx % 96; int tmp = idx / 96; int h = tmp % 96; tmp /= 96; int c = tmp % 64; int b = tmp / 64;
  const float* src = x + (b * 256 + 128 + c) * 9216;
  float m = -3.4e38f;
  for (int dy = -1; dy <= 1; ++dy) {
    int y = h + dy; if ((unsigned)y >= 96u) continue;
    for (int dx = -1; dx <= 1; ++dx) {
      int xx = wpx + dx; if ((unsigned)xx >= 96u) continue;
      m = fmaxf(m, src[y * 96 + xx]);
    }
  }
  out[idx] = m;
}

// ---------------- blurpool -------------------------------------------------------------------
__global__ __launch_bounds__(256) void k_blur(const float* __restrict__ in, float* __restrict__ out) {
  int idx = blockIdx.x * 256 + threadIdx.x;
  if (idx >= 16 * 64 * 1024) return;
  int ow = idx % 32; int tmp = idx / 32; int oh = tmp % 32; int bc = tmp / 32;
  const float* src = in + bc * 9216;
  const float a4[4] = {1.f, 3.f, 3.f, 1.f};
  float s = 0.f;
  for (int ky = 0; ky < 4; ++ky) {
    int sy = 3 * oh + ky - 1; if (sy < 0) sy = -sy; if (sy > 95) sy = 190 - sy;
    for (int kx = 0; kx < 4; ++kx) {
      int sx = 3 * ow + kx - 1; if (sx < 0) sx = -sx; if (sx > 95) sx = 190 - sx;
      s += a4[ky] * a4[kx] * src[sy * 96 + sx];
    }
  }
  out[idx] = s * (1.0f / 64.0f);
}

// ---------------- generic depthwise conv ----------------------------------------------------
__global__ __launch_bounds__(256) void k_dw(const float* __restrict__ in, const float* __restrict__ w,
    const float* __restrict__ bias, float* __restrict__ out,
    int H, int W, int KH, int KW, int pH, int pW, int dil, int accf) {
  int idx = blockIdx.x * 256 + threadIdx.x;
  int total = 16 * 64 * H * W; if (idx >= total) return;
  int wpx = idx % W; int tmp = idx / W; int h = tmp % H; tmp /= H; int c = tmp % 64;
  const float* src = in + tmp * H * W;
  const float* wr = w + c * KH * KW;
  float a = bias ? bias[c] : 0.f;
  for (int ky = 0; ky < KH; ++ky) {
    int y = h - pH + ky * dil; if ((unsigned)y >= (unsigned)H) continue;
    for (int kx = 0; kx < KW; ++kx) {
      int xx = wpx - pW + kx * dil; if ((unsigned)xx >= (unsigned)W) continue;
      a += wr[ky * KW + kx] * src[y * W + xx];
    }
  }
  if (accf) out[idx] += a; else out[idx] = a;
}

// ---------------- shear transforms ----------------------------------------------------------
__global__ __launch_bounds__(256) void k_htrans(const float* __restrict__ in, float* __restrict__ out) {
  int idx = blockIdx.x * 256 + threadIdx.x;
  if (idx >= 16 * 64 * 32 * 63) return;
  int j = idx % 63; int tmp = idx / 63; int i = tmp % 32; int bc = tmp / 32;
  int k = j - i;
  out[idx] = (k >= 0 && k < 32) ? in[(bc * 32 + i) * 32 + k] : 0.f;
}
__global__ __launch_bounds__(256) void k_invh_add(const float* __restrict__ F, float* __restrict__ D) {
  int idx = blockIdx.x * 256 + threadIdx.x;
  if (idx >= 16 * 64 * 1024) return;
  int j = idx % 32; int tmp = idx / 32; int i = tmp % 32; int bc = tmp / 32;
  D[idx] += F[(bc * 32 + i) * 63 + i + j];
}
__global__ __launch_bounds__(256) void k_vtrans(const float* __restrict__ in, float* __restrict__ out) {
  int idx = blockIdx.x * 256 + threadIdx.x;
  if (idx >= 16 * 64 * 63 * 32) return;
  int c = idx % 32; int tmp = idx / 32; int r = tmp % 63; int bc = tmp / 63;
  int k = r - c;
  out[idx] = (k >= 0 && k < 32) ? in[(bc * 32 + k) * 32 + c] : 0.f;
}
__global__ __launch_bounds__(256) void k_invv_add(const float* __restrict__ F, float* __restrict__ D) {
  int idx = blockIdx.x * 256 + threadIdx.x;
  if (idx >= 16 * 64 * 1024) return;
  int j = idx % 32; int tmp = idx / 32; int i = tmp % 32; int bc = tmp / 32;
  D[idx] += F[(bc * 63 + (i + j)) * 32 + j];
}

// ---------------- gate ----------------------------------------------------------------------
__global__ __launch_bounds__(256) void k_gate(const float* __restrict__ D, const float* __restrict__ x,
    const float* __restrict__ g, const float* __restrict__ bb,
    float* __restrict__ mra_out, bf16* __restrict__ xa) {
  int idx = blockIdx.x * 256 + threadIdx.x;
  if (idx >= 16 * 64 * 9216) return;
  int wv = idx % 96; int tmp = idx / 96; int h = tmp % 96; tmp /= 96; int c = tmp % 64; int b = tmp / 64;
  float d = D[((b * 64 + c) * 32 + h / 3) * 32 + (wv / 3)];
  float gt = sigmf(d * g[c] * BNS + bb[c]);
  float x3v = x[(b * 256 + 128 + c) * 9216 + h * 96 + wv];
  float mra = x3v * gt;
  mra_out[idx] = mra;
  xa[(b * 256 + 128 + c) * 9216 + h * 96 + wv] = __float2bfloat16(x3v + mra);
}

// ---------------- maxpool2 with argmax ------------------------------------------------------
__global__ __launch_bounds__(256) void k_pool2(const float* __restrict__ in, float* __restrict__ out,
                                               int* __restrict__ idxo) {
  int idx = blockIdx.x * 256 + threadIdx.x;
  if (idx >= 16 * 64 * 2304) return;
  int ow = idx % 48; int tmp = idx / 48; int oh = tmp % 48; int bc = tmp / 48;
  const float* src = in + bc * 9216;
  int y = 2 * oh, xx = 2 * ow;
  float v0 = src[y * 96 + xx], v1 = src[y * 96 + xx + 1];
  float v2 = src[(y + 1) * 96 + xx], v3 = src[(y + 1) * 96 + xx + 1];
  float best = v0; int bi = 0;
  if (v1 > best) { best = v1; bi = 1; }
  if (v2 > best) { best = v2; bi = 2; }
  if (v3 > best) { best = v3; bi = 3; }
  out[idx] = best; idxo[idx] = bi;
}

// ---------------- channel mean/max ----------------------------------------------------------
__global__ __launch_bounds__(256) void k_agg(const float* __restrict__ J, const float* __restrict__ K,
                                             float* __restrict__ AGG) {
  int idx = blockIdx.x * 256 + threadIdx.x;
  if (idx >= 16 * 2304) return;
  int hw = idx % 2304; int b = idx / 2304;
  float sum = 0.f, mx = -3.4e38f;
  for (int j = 0; j < 32; ++j) { float v = J[(b * 32 + j) * 2304 + hw]; sum += v; mx = fmaxf(mx, v); }
  for (int j = 0; j < 32; ++j) { float v = K[(b * 32 + j) * 2304 + hw]; sum += v; mx = fmaxf(mx, v); }
  AGG[(b * 2 + 0) * 2304 + hw] = sum * (1.0f / 64.0f);
  AGG[(b * 2 + 1) * 2304 + hw] = mx;
}

// ---------------- squeeze conv 2->2 7x7 pad3 + sigmoid --------------------------------------
__global__ __launch_bounds__(256) void k_sq(const float* __restrict__ AGG, const float* __restrict__ w,
                                            const float* __restrict__ bias, float* __restrict__ SG) {
  int idx = blockIdx.x * 256 + threadIdx.x;
  if (idx >= 16 * 2 * 2304) return;
  int hw = idx % 2304; int tmp = idx / 2304; int co = tmp % 2; int b = tmp / 2;
  int h = hw / 48, wv = hw % 48;
  float acc = bias[co];
  for (int ci = 0; ci < 2; ++ci) {
    const float* src = AGG + (b * 2 + ci) * 2304;
    for (int ky = 0; ky < 7; ++ky) {
      int y = h - 3 + ky; if ((unsigned)y >= 48u) continue;
      for (int kx = 0; kx < 7; ++kx) {
        int xx = wv - 3 + kx; if ((unsigned)xx >= 48u) continue;
        acc += w[((co * 2 + ci) * 7 + ky) * 7 + kx] * src[y * 48 + xx];
      }
    }
  }
  SG[idx] = sigmf(acc);
}

__global__ __launch_bounds__(256) void k_mix(const float* __restrict__ J, const float* __restrict__ K,
                                             const float* __restrict__ SG, float* __restrict__ L) {
  int idx = blockIdx.x * 256 + threadIdx.x;
  if (idx >= 16 * 32 * 2304) return;
  int hw = idx % 2304; int tmp = idx / 2304; int b = tmp / 32;
  L[idx] = J[idx] * SG[(b * 2) * 2304 + hw] + K[idx] * SG[(b * 2 + 1) * 2304 + hw];
}

__global__ __launch_bounds__(256) void k_mul(const float* __restrict__ A, const float* __restrict__ B,
                                             float* __restrict__ O) {
  int idx = blockIdx.x * 256 + threadIdx.x;
  if (idx >= 16 * 64 * 2304) return;
  O[idx] = A[idx] * B[idx];
}

// ---------------- unpool + bn(n4), xa ch192..255 --------------------------------------------
__global__ __launch_bounds__(256) void k_unpool(const float* __restrict__ N2, const int* __restrict__ IDX,
    const float* __restrict__ x, const float* __restrict__ g, const float* __restrict__ bb,
    bf16* __restrict__ xa) {
  int idx = blockIdx.x * 256 + threadIdx.x;
  if (idx >= 16 * 64 * 9216) return;
  int wv = idx % 96; int tmp = idx / 96; int h = tmp % 96; tmp /= 96; int c = tmp % 64; int b = tmp / 64;
  int oh = h >> 1, ow = wv >> 1;
  int pos = (b * 64 + c) * 2304 + oh * 48 + ow;
  int kk = (h & 1) * 2 + (wv & 1);
  float v = (IDX[pos] == kk) ? N2[pos] : 0.f;
  float x4v = x[(b * 256 + 192 + c) * 9216 + h * 96 + wv];
  xa[(b * 256 + 192 + c) * 9216 + h * 96 + wv] =
      __float2bfloat16((x4v + v) * g[c] * BNS + bb[c]);
}

// ---------------- transpose XA (ch-major bf16) -> XAT (pixel-major bf16) --------------------
__global__ __launch_bounds__(256) void k_tr(const unsigned short* __restrict__ XA,
                                            unsigned short* __restrict__ XAT) {
  __shared__ unsigned s[64][65];
  int t = threadIdx.x;
  int bid = blockIdx.x;
  int ct = bid & 3;
  int pt = (bid >> 2) % 144;
  int b = (bid >> 2) / 144;
  int c0 = ct * 64, p0 = pt * 64;
  for (int i = t; i < 4096; i += 256) {
    int cl = i >> 6, pl = i & 63;
    s[cl][pl] = XA[(size_t)(b * 256 + c0 + cl) * 9216 + p0 + pl];
  }
  __syncthreads();
  for (int i = t; i < 4096; i += 256) {
    int pl = i >> 6, cl = i & 63;
    XAT[((size_t)(b * 9216 + p0 + pl) << 8) + c0 + cl] = (unsigned short)s[cl][pl];
  }
}

// ---------------- prep: pack weights frag-linear, bf16, BN scales folded --------------------
// W1P: idx = ((mb*8 + ks)*64 + lane)*8 + j ; h = mb*16+(lane&15), k = ks*32+(lane>>4)*8+j
// W2P: idx = ((c*16 + mb)*64 + lane)*8 + j ; m = mb*16+(lane&15), k = c*32+(lane>>4)*8+j
__global__ __launch_bounds__(256) void k_prep(const float* __restrict__ w1, const float* __restrict__ g1,
    const float* __restrict__ w2, const float* __restrict__ ng,
    unsigned short* __restrict__ w1p, unsigned short* __restrict__ w2p) {
  int i = blockIdx.x * 256 + threadIdx.x;
  if (i >= 262144) return;
  {
    int j = i & 7, lane = (i >> 3) & 63, ks = (i >> 9) & 7, mb = i >> 12;
    int h = mb * 16 + (lane & 15);
    int k = ks * 32 + (lane >> 4) * 8 + j;
    w1p[i] = f2b(w1[h * 256 + k] * (g1[h] * BNS));
  }
  {
    int j = i & 7, lane = (i >> 3) & 63, mb = (i >> 9) & 15, c = i >> 13;
    int m = mb * 16 + (lane & 15);
    int k = c * 32 + (lane >> 4) * 8 + j;
    w2p[i] = f2b(w2[m * 1024 + k] * (ng[m] * BNS));
  }
}

// ---------------- fused MFMA MLP v2: blocked GEMM, B-in-registers, W staged in LDS ----------
// 1152 blocks x 256 thr (4 waves). Block = 128 pixels. 32 chunks of 32 hidden.
// GEMM1: Hc[2][2] (2 mb x 2 nt) ; GEMM2: Y[16][2].
__global__ __launch_bounds__(256, 2) void k_mlp_mfma(
    const unsigned short* __restrict__ XAT,
    const unsigned short* __restrict__ W1P, const float* __restrict__ b1,
    const unsigned short* __restrict__ W2P, const float* __restrict__ nbv,
    const float* __restrict__ xin, float* __restrict__ out) {
  __shared__ uint4 w1c4[1024];             // 16 KB: [mbl2][ks8][lane64] x 16B
  __shared__ uint4 w2c4[1024];             // 16 KB: [mb16][lane64] x 16B
  __shared__ unsigned short hs[128][56];   // 14 KB (pad 56: rows 16B-aligned)
  __shared__ float b1s[1024];
  __shared__ float nbs[256];
  unsigned short* w1c = (unsigned short*)w1c4;
  unsigned short* w2c = (unsigned short*)w2c4;
  int t = threadIdx.x;
  int b = blockIdx.x / 72;
  int hw0 = (blockIdx.x % 72) * 128;
  for (int i = t; i < 1024; i += 256) b1s[i] = b1[i];
  nbs[t] = nbv[t];
  int lane = t & 63, wave = t >> 6;
  int lm = lane & 15, lk = lane >> 4;
  // preload all activation B-frags for this lane (reused across all 32 chunks)
  bf16x8 Bf[2][8];
  {
    const unsigned short* base = XAT + ((size_t)(b * 9216 + hw0 + wave * 32 + lm) << 8) + lk * 8;
#pragma unroll
    for (int nt2 = 0; nt2 < 2; ++nt2)
#pragma unroll
      for (int ks = 0; ks < 8; ++ks)
        Bf[nt2][ks] = *(const bf16x8*)(base + nt2 * 16 * 256 + ks * 32);
  }
  f32x4 Y[16][2];
#pragma unroll
  for (int i = 0; i < 16; ++i) { Y[i][0] = (f32x4){0,0,0,0}; Y[i][1] = (f32x4){0,0,0,0}; }

  const uint4* g1p = (const uint4*)W1P;
  const uint4* g2p = (const uint4*)W2P;
  for (int c = 0; c < 32; ++c) {
    __syncthreads();  // previous chunk's LDS reads complete before overwrite
#pragma unroll
    for (int i = 0; i < 4; ++i) {
      int o = i * 256 + t;
      w1c4[o] = g1p[c * 1024 + o];
      w2c4[o] = g2p[c * 1024 + o];
    }
    __syncthreads();
    // GEMM1: H chunk (32 hidden x 32 pixels per wave)
    f32x4 Hc[2][2];
#pragma unroll
    for (int i = 0; i < 2; ++i) { Hc[i][0] = (f32x4){0,0,0,0}; Hc[i][1] = (f32x4){0,0,0,0}; }
#pragma unroll
    for (int ks = 0; ks < 8; ++ks) {
      bf16x8 a0 = *(const bf16x8*)&w1c[(ks * 64 + lane) * 8];
      bf16x8 a1 = *(const bf16x8*)&w1c[((8 + ks) * 64 + lane) * 8];
      Hc[0][0] = __builtin_amdgcn_mfma_f32_16x16x32_bf16(a0, Bf[0][ks], Hc[0][0], 0, 0, 0);
      Hc[0][1] = __builtin_amdgcn_mfma_f32_16x16x32_bf16(a0, Bf[1][ks], Hc[0][1], 0, 0, 0);
      Hc[1][0] = __builtin_amdgcn_mfma_f32_16x16x32_bf16(a1, Bf[0][ks], Hc[1][0], 0, 0, 0);
      Hc[1][1] = __builtin_amdgcn_mfma_f32_16x16x32_bf16(a1, Bf[1][ks], Hc[1][1], 0, 0, 0);
    }
    // gelu + bias, write hs (wave-private rows [wave*32, wave*32+32))
#pragma unroll
    for (int mbl = 0; mbl < 2; ++mbl)
#pragma unroll
      for (int nt2 = 0; nt2 < 2; ++nt2)
#pragma unroll
        for (int r = 0; r < 4; r += 2) {
          int h = c * 32 + mbl * 16 + lk * 4 + r;
          float v0 = geluf(Hc[mbl][nt2][r]     + b1s[h]);
          float v1 = geluf(Hc[mbl][nt2][r + 1] + b1s[h + 1]);
          unsigned u = (unsigned)f2b(v0) | ((unsigned)f2b(v1) << 16);
          *(unsigned*)&hs[wave * 32 + nt2 * 16 + lm][mbl * 16 + lk * 4 + r] = u;
        }
    // GEMM2: accumulate Y over this chunk's K=32 (wave-private hs, no barrier)
    bf16x8 h0 = *(const bf16x8*)&hs[wave * 32 + lm][lk * 8];
    bf16x8 h1 = *(const bf16x8*)&hs[wave * 32 + 16 + lm][lk * 8];
#pragma unroll
    for (int mb = 0; mb < 16; ++mb) {
      bf16x8 a = *(const bf16x8*)&w2c[(mb * 64 + lane) * 8];
      Y[mb][0] = __builtin_amdgcn_mfma_f32_16x16x32_bf16(a, h0, Y[mb][0], 0, 0, 0);
      Y[mb][1] = __builtin_amdgcn_mfma_f32_16x16x32_bf16(a, h1, Y[mb][1], 0, 0, 0);
    }
  }
  // epilogue: Y + bias + residual
#pragma unroll
  for (int mb = 0; mb < 16; ++mb)
#pragma unroll
    for (int nt2 = 0; nt2 < 2; ++nt2)
#pragma unroll
      for (int r = 0; r < 4; ++r) {
        int m = mb * 16 + lk * 4 + r;
        size_t o = (size_t)(b * 256 + m) * 9216 + hw0 + wave * 32 + nt2 * 16 + lm;
        out[o] = Y[mb][nt2][r] + nbs[m] + xin[o];
      }
}

extern "C" void kernel_launch(void* const* d_in, const int* in_sizes, int n_in,
                              void* d_out, int out_size, void* d_ws, size_t ws_size,
                              hipStream_t stream) {
  const float* x        = (const float*)d_in[0];
  const float* pa_w1    = (const float*)d_in[1];
  const float* pa_bn_g  = (const float*)d_in[2];
  const float* pa_bn_b  = (const float*)d_in[3];
  const float* pa_w2    = (const float*)d_in[4];
  const float* fuse1_w  = (const float*)d_in[5];
  const float* la_w     = (const float*)d_in[6];
  const float* la_bn_g  = (const float*)d_in[7];
  const float* la_bn_b  = (const float*)d_in[8];
  const float* h1_w     = (const float*)d_in[9];
  const float* v1_w     = (const float*)d_in[10];
  const float* h2_w     = (const float*)d_in[11];
  const float* v2_w     = (const float*)d_in[12];
  const float* mra_bn_g = (const float*)d_in[13];
  const float* mra_bn_b = (const float*)d_in[14];
  const float* fuse2_w  = (const float*)d_in[15];
  const float* g_p1_w   = (const float*)d_in[16];
  const float* g_p1_b   = (const float*)d_in[17];
  const float* g_c0_w   = (const float*)d_in[18];
  const float* g_c0_b   = (const float*)d_in[19];
  const float* g_cs_w   = (const float*)d_in[20];
  const float* g_cs_b   = (const float*)d_in[21];
  const float* g_c1_w   = (const float*)d_in[22];
  const float* g_c1_b   = (const float*)d_in[23];
  const float* g_c2_w   = (const float*)d_in[24];
  const float* g_c2_b   = (const float*)d_in[25];
  const float* g_sq_w   = (const float*)d_in[26];
  const float* g_sq_b   = (const float*)d_in[27];
  const float* g_cv_w   = (const float*)d_in[28];
  const float* g_cv_b   = (const float*)d_in[29];
  const float* g_p2_w   = (const float*)d_in[30];
  const float* g_p2_b   = (const float*)d_in[31];
  const float* n4_g     = (const float*)d_in[32];
  const float* n4_b     = (const float*)d_in[33];
  const float* mlp_w1   = (const float*)d_in[34];
  const float* mlp_bn_g = (const float*)d_in[35];
  const float* mlp_bn_b = (const float*)d_in[36];
  const float* mlp_w2   = (const float*)d_in[37];
  const float* n1_g     = (const float*)d_in[38];
  const float* n1_b     = (const float*)d_in[39];

  // ---- aliased workspace: 44,236,800 floats = 176.9 MB ----
  float* ws = (float*)d_ws;
  bf16*  XA = (bf16*)ws;                    // (16,256,96,96) bf16, ch-major = 18,874,368 f-slots
  float* P  = ws + 18874368;                // 9,437,184 f
  float* Q  = ws + 28311552;                // 9,437,184 f
  float* R  = ws + 37748736;                // 6,225,920 f
  float* T  = R;
  float* D  = R + 1048576;
  float* E  = R + 2097152;
  float* F  = R + 4161536;
  float* C48 = P;
  int*   IDX = (int*)(P + 2359296);
  float* G   = P + 4718592;
  float* H2  = P + 7077888;
  float* I2  = Q;
  float* M   = Q + 2359296;
  float* XM  = Q + 4718592;
  float* N2  = Q + 7077888;
  float* J   = R;
  float* K2  = R + 1179648;
  float* L   = R + 2359296;
  float* AGG = R + 3538944;
  float* SG  = R + 3612672;
  // XAT (pixel-major bf16) overlays P+Q after the GA branch is done
  unsigned short* XAT = (unsigned short*)P;                 // 18,874,368 shorts = 75.5 MB
  unsigned short* W1P = (unsigned short*)(ws + 43974656);   // 262144 bf16
  unsigned short* W2P = (unsigned short*)(ws + 43974656 + 131072);

  // Prep (independent): packed bf16 weights, BN scales folded
  k_prep<<<1024, 256, 0, stream>>>(mlp_w1, mlp_bn_g, mlp_w2, n1_g, W1P, W2P);
  // Branch 1 (PA) -> x1pa (P), xa ch 0..63
  k_pa<<<9216, 256, 0, stream>>>(x, pa_w1, pa_bn_g, pa_bn_b, pa_w2, P, XA);
  // Branch 2: fuse1 -> Q; la -> xa ch 64..127
  k_conv1x1<<<2304, 256, 0, stream>>>(P, 64, x, 64, 64, fuse1_w, (const float*)nullptr, 0, Q, 64, 9216);
  k_la<<<36864, 256, 0, stream>>>(Q, la_w, la_bn_g, la_bn_b, XA);
  // Branch 3 (MRA)
  k_maxpool3<<<36864, 256, 0, stream>>>(x, P);
  k_blur<<<4096, 256, 0, stream>>>(P, T);
  k_dw<<<4096, 256, 0, stream>>>(T, h1_w, (const float*)nullptr, D, 32, 32, 7, 3, 3, 1, 1, 0);
  k_dw<<<4096, 256, 0, stream>>>(T, v1_w, (const float*)nullptr, D, 32, 32, 3, 7, 1, 3, 1, 1);
  k_htrans<<<8064, 256, 0, stream>>>(T, E);
  k_dw<<<8064, 256, 0, stream>>>(E, h2_w, (const float*)nullptr, F, 32, 63, 7, 3, 3, 1, 1, 0);
  k_invh_add<<<4096, 256, 0, stream>>>(F, D);
  k_vtrans<<<8064, 256, 0, stream>>>(T, E);
  k_dw<<<8064, 256, 0, stream>>>(E, v2_w, (const float*)nullptr, F, 63, 32, 3, 7, 1, 3, 1, 0);
  k_invv_add<<<4096, 256, 0, stream>>>(F, D);
  k_gate<<<36864, 256, 0, stream>>>(D, x, mra_bn_g, mra_bn_b, P, XA);
  // Branch 4 (GA)
  k_conv1x1<<<2304, 256, 0, stream>>>(P, 64, x, 192, 64, fuse2_w, (const float*)nullptr, 0, Q, 64, 9216);
  k_pool2<<<9216, 256, 0, stream>>>(Q, C48, IDX);
  k_conv1x1<<<576, 256, 0, stream>>>(C48, 64, (const float*)nullptr, 0, 0, g_p1_w, g_p1_b, 1, G, 64, 2304);
  k_dw<<<9216, 256, 0, stream>>>(G, g_c0_w, g_c0_b, H2, 48, 48, 5, 5, 2, 2, 1, 0);
  k_dw<<<9216, 256, 0, stream>>>(H2, g_cs_w, g_cs_b, I2, 48, 48, 7, 7, 9, 9, 3, 0);
  k_conv1x1<<<576, 256, 0, stream>>>(H2, 64, (const float*)nullptr, 0, 0, g_c1_w, g_c1_b, 0, J, 32, 2304);
  k_conv1x1<<<576, 256, 0, stream>>>(I2, 64, (const float*)nullptr, 0, 0, g_c2_w, g_c2_b, 0, K2, 32, 2304);
  k_agg<<<144, 256, 0, stream>>>(J, K2, AGG);
  k_sq<<<288, 256, 0, stream>>>(AGG, g_sq_w, g_sq_b, SG);
  k_mix<<<4608, 256, 0, stream>>>(J, K2, SG, L);
  k_conv1x1<<<576, 256, 0, stream>>>(L, 32, (const float*)nullptr, 0, 0, g_cv_w, g_cv_b, 0, M, 64, 2304);
  k_mul<<<9216, 256, 0, stream>>>(G, M, XM);
  k_conv1x1<<<576, 256, 0, stream>>>(XM, 64, (const float*)nullptr, 0, 0, g_p2_w, g_p2_b, 0, N2, 64, 2304);
  k_unpool<<<36864, 256, 0, stream>>>(N2, IDX, x, n4_g, n4_b, XA);
  // Transpose xa -> pixel-major (P/Q dead now)
  k_tr<<<9216, 256, 0, stream>>>((const unsigned short*)XA, XAT);
  // MLP + residual (blocked MFMA)
  k_mlp_mfma<<<1152, 256, 0, stream>>>(XAT, W1P, mlp_bn_b, W2P, n1_b, x, (float*)d_out);
}